// Round 1
// baseline (46.319 us; speedup 1.0000x reference)
//
#include <hip/hip_runtime.h>

// Problem constants (from reference): B=8, X=Y=Z=128, f32 in/out.
#define NB 8
#define NX 128
#define NY 128
#define NZ 128
// z handled 4-at-a-time per thread
#define ZQ (NZ / 4)   // 32

__global__ __launch_bounds__(256) void lap_kernel(
    const float* __restrict__ mu,
    const float* __restrict__ act,
    const float* __restrict__ dxp,
    float* __restrict__ out)
{
    int t = blockIdx.x * blockDim.x + threadIdx.x;
    // bits: zq[0:5) y[5:12) x[12:19) b[19:22)
    int zq = t & (ZQ - 1);
    int y  = (t >> 5) & (NY - 1);
    int x  = (t >> 12) & (NX - 1);
    int b  = t >> 19;
    if (b >= NB) return;

    const int z0 = zq * 4;
    const int planeYZ = NY * NZ;          // 16384
    const int baseB = b * NX * planeYZ;   // fits in int (max 16M)

    const float dx = dxp[0];
    const float inv = 1.0f / (dx * dx);

    // center row
    const int cIdx = baseB + x * planeYZ + y * NZ + z0;
    float4 mc = *reinterpret_cast<const float4*>(mu + cIdx);
    float4 ac = *reinterpret_cast<const float4*>(act + cIdx);
    float4 ec = make_float4(mc.x * ac.x, mc.y * ac.y, mc.z * ac.z, mc.w * ac.w);

    // z wrap neighbors (scalar)
    const int zm = (z0 - 1) & (NZ - 1);
    const int zp = (z0 + 4) & (NZ - 1);
    const int rowBase = baseB + x * planeYZ + y * NZ;
    float e_zm = mu[rowBase + zm] * act[rowBase + zm];
    float e_zp = mu[rowBase + zp] * act[rowBase + zp];

    // x neighbors
    const int xm = (x - 1) & (NX - 1);
    const int xp = (x + 1) & (NX - 1);
    const int xmIdx = baseB + xm * planeYZ + y * NZ + z0;
    const int xpIdx = baseB + xp * planeYZ + y * NZ + z0;
    float4 m_xm = *reinterpret_cast<const float4*>(mu + xmIdx);
    float4 a_xm = *reinterpret_cast<const float4*>(act + xmIdx);
    float4 m_xp = *reinterpret_cast<const float4*>(mu + xpIdx);
    float4 a_xp = *reinterpret_cast<const float4*>(act + xpIdx);

    // y neighbors
    const int ym = (y - 1) & (NY - 1);
    const int yp = (y + 1) & (NY - 1);
    const int ymIdx = baseB + x * planeYZ + ym * NZ + z0;
    const int ypIdx = baseB + x * planeYZ + yp * NZ + z0;
    float4 m_ym = *reinterpret_cast<const float4*>(mu + ymIdx);
    float4 a_ym = *reinterpret_cast<const float4*>(act + ymIdx);
    float4 m_yp = *reinterpret_cast<const float4*>(mu + ypIdx);
    float4 a_yp = *reinterpret_cast<const float4*>(act + ypIdx);

    float4 e_xm = make_float4(m_xm.x * a_xm.x, m_xm.y * a_xm.y, m_xm.z * a_xm.z, m_xm.w * a_xm.w);
    float4 e_xp = make_float4(m_xp.x * a_xp.x, m_xp.y * a_xp.y, m_xp.z * a_xp.z, m_xp.w * a_xp.w);
    float4 e_ym = make_float4(m_ym.x * a_ym.x, m_ym.y * a_ym.y, m_ym.z * a_ym.z, m_ym.w * a_ym.w);
    float4 e_yp = make_float4(m_yp.x * a_yp.x, m_yp.y * a_yp.y, m_yp.z * a_yp.z, m_yp.w * a_yp.w);

    float4 r;
    r.x = (e_xm.x + e_xp.x + e_ym.x + e_yp.x + e_zm + ec.y - 6.0f * ec.x) * inv * ac.x;
    r.y = (e_xm.y + e_xp.y + e_ym.y + e_yp.y + ec.x + ec.z - 6.0f * ec.y) * inv * ac.y;
    r.z = (e_xm.z + e_xp.z + e_ym.z + e_yp.z + ec.y + ec.w - 6.0f * ec.z) * inv * ac.z;
    r.w = (e_xm.w + e_xp.w + e_ym.w + e_yp.w + ec.z + e_zp - 6.0f * ec.w) * inv * ac.w;

    *reinterpret_cast<float4*>(out + cIdx) = r;
}

extern "C" void kernel_launch(void* const* d_in, const int* in_sizes, int n_in,
                              void* d_out, int out_size, void* d_ws, size_t ws_size,
                              hipStream_t stream) {
    const float* mu  = (const float*)d_in[0];
    const float* act = (const float*)d_in[1];
    const float* dx  = (const float*)d_in[2];
    float* out = (float*)d_out;

    const int total_threads = NB * NX * NY * ZQ;  // 4,194,304
    const int block = 256;
    const int grid = total_threads / block;        // 16384
    lap_kernel<<<grid, block, 0, stream>>>(mu, act, dx, out);
}

// Round 2
// 39.558 us; speedup vs baseline: 1.1709x; 1.1709x over previous
//
#include <hip/hip_runtime.h>

// B=8, X=Y=Z=128, f32. Periodic 7-point Laplacian of (mu*active), times active.
#define NB 8
#define NX 128
#define NY 128
#define NZ 128

#define TY 16            // y-rows per block
#define TX 8             // x-planes per block
#define XC (NX / TX)     // 16 x-chunks
#define YT (NY / TY)     // 8 y-tiles
#define PLANE_ROWS (TY + 2)

__global__ __launch_bounds__(256) void lap_lds(
    const float* __restrict__ mu,
    const float* __restrict__ act,
    const float* __restrict__ dxp,
    float* __restrict__ out)
{
    // e = mu*act ring buffer: 3 x-planes of (TY+2) y-rows x 128 z
    __shared__ float e[3][PLANE_ROWS][NZ];   // 27648 B

    const int tid = threadIdx.x;
    const int bid = blockIdx.x;
    const int xc = bid & (XC - 1);
    const int yt = (bid >> 4) & (YT - 1);
    const int b  = bid >> 7;

    const int x0 = xc * TX;
    const int y0 = yt * TY;
    const int planeYZ = NY * NZ;           // 16384
    const int baseB = b * NX * planeYZ;    // max ~16.7M, fits int

    const float dxv = dxp[0];
    const float inv = 1.0f / (dxv * dxv);

    float4 A[2];   // act for the plane currently being computed
    float4 Bt[2];  // act for the plane just loaded

    // load plane at global x = gx into ring slot `slot`; keep center act in keepA
    auto load_plane = [&](int gx, int slot, float4* keepA) {
        const int px = baseB + gx * planeYZ;
        #pragma unroll
        for (int k = 0; k < 2; ++k) {
            const int qi = tid + k * 256;      // 0..511
            const int r  = qi >> 5;            // 0..15 (center rows)
            const int zq = qi & 31;
            const int gIdx = px + (y0 + r) * NZ + zq * 4;
            float4 m = *reinterpret_cast<const float4*>(mu + gIdx);
            float4 a = *reinterpret_cast<const float4*>(act + gIdx);
            keepA[k] = a;
            float4 ev = make_float4(m.x * a.x, m.y * a.y, m.z * a.z, m.w * a.w);
            *reinterpret_cast<float4*>(&e[slot][r + 1][zq * 4]) = ev;
        }
        if (tid < 64) {
            const int hr = tid >> 5;           // 0: y-1 halo, 1: y+TY halo
            const int zq = tid & 31;
            const int gy = hr ? ((y0 + TY) & (NY - 1)) : ((y0 - 1) & (NY - 1));
            const int lr = hr ? (TY + 1) : 0;
            const int gIdx = px + gy * NZ + zq * 4;
            float4 m = *reinterpret_cast<const float4*>(mu + gIdx);
            float4 a = *reinterpret_cast<const float4*>(act + gIdx);
            float4 ev = make_float4(m.x * a.x, m.y * a.y, m.z * a.z, m.w * a.w);
            *reinterpret_cast<float4*>(&e[slot][lr][zq * 4]) = ev;
        }
    };

    // slot(lp) = (lp+1) % 3 for local plane lp in [-1, TX]
    load_plane((x0 - 1) & (NX - 1), 0, Bt);   // lp=-1 halo (act discarded)
    load_plane(x0, 1, A);                      // lp=0

    for (int i = 0; i < TX; ++i) {
        const int sm = i % 3;            // slot(i-1)
        const int sc = (i + 1) % 3;      // slot(i)
        const int sp = (i + 2) % 3;      // slot(i+1)

        load_plane((x0 + i + 1) & (NX - 1), sp, Bt);   // lp=i+1
        __syncthreads();

        const int gx = x0 + i;           // in [x0, x0+TX), no wrap needed
        const int px = baseB + gx * planeYZ;
        #pragma unroll
        for (int k = 0; k < 2; ++k) {
            const int qi = tid + k * 256;
            const int r  = qi >> 5;
            const int zq = qi & 31;
            const int z0 = zq * 4;
            float4 ec  = *reinterpret_cast<const float4*>(&e[sc][r + 1][z0]);
            float4 exm = *reinterpret_cast<const float4*>(&e[sm][r + 1][z0]);
            float4 exP = *reinterpret_cast<const float4*>(&e[sp][r + 1][z0]);
            float4 eym = *reinterpret_cast<const float4*>(&e[sc][r][z0]);
            float4 eyp = *reinterpret_cast<const float4*>(&e[sc][r + 2][z0]);
            float ezm = e[sc][r + 1][(z0 - 1) & (NZ - 1)];
            float ezp = e[sc][r + 1][(z0 + 4) & (NZ - 1)];
            float4 a = A[k];
            float4 o;
            o.x = (exm.x + exP.x + eym.x + eyp.x + ezm + ec.y - 6.0f * ec.x) * inv * a.x;
            o.y = (exm.y + exP.y + eym.y + eyp.y + ec.x + ec.z - 6.0f * ec.y) * inv * a.y;
            o.z = (exm.z + exP.z + eym.z + eyp.z + ec.y + ec.w - 6.0f * ec.z) * inv * a.z;
            o.w = (exm.w + exP.w + eym.w + eyp.w + ec.z + ezp - 6.0f * ec.w) * inv * a.w;
            const int gIdx = px + (y0 + r) * NZ + z0;
            *reinterpret_cast<float4*>(out + gIdx) = o;
        }

        A[0] = Bt[0];
        A[1] = Bt[1];
        __syncthreads();   // before next load overwrites slot sm
    }
}

extern "C" void kernel_launch(void* const* d_in, const int* in_sizes, int n_in,
                              void* d_out, int out_size, void* d_ws, size_t ws_size,
                              hipStream_t stream) {
    const float* mu  = (const float*)d_in[0];
    const float* act = (const float*)d_in[1];
    const float* dx  = (const float*)d_in[2];
    float* out = (float*)d_out;

    const int grid = NB * YT * XC;   // 1024 blocks
    lap_lds<<<grid, 256, 0, stream>>>(mu, act, dx, out);
}